// Round 9
// baseline (169.976 us; speedup 1.0000x reference)
//
#include <hip/hip_runtime.h>

typedef unsigned short ushort_t;
typedef __attribute__((ext_vector_type(8))) short short8;   // 8 bf16 payload (4 VGPRs)
typedef __attribute__((ext_vector_type(4))) float floatx4;  // MFMA C/D
typedef __attribute__((ext_vector_type(2))) float floatx2;  // packed fp32 (VOP3P)

#define NN    32
#define CIN   128
#define COUT  256
#define NPTS  16384            // bs*v = 4*4096
#define NSAMP (NPTS * NN)      // 524288
#define LDA   136              // LDS A-tile stride (+16B pad)
#define YBLK  256              // ygemm grid (NPTS/64)

// Scratch in .so-resident device globals. SELF-CLEANING invariant: g_mult,
// g_stat, g_done are zero at kernel_launch entry (BSS-zero on load; each
// call re-zeroes them after use), so no zeroing dispatch is needed.
__device__ ushort_t g_wb[COUT * CIN];            // 64 KB: W as bf16
__device__ ushort_t g_y[(size_t)NPTS * COUT];    // 8 MB: Y = fsp * W^T, bf16
__device__ int      g_mult[NPTS];                // gather multiplicity histogram
__device__ float    g_stat[512];                 // sum[256] ++ sumsq[256]
__device__ float    g_consts[1536];              // scale,shift,d0,s0,s1,s2 per ch
__device__ int      g_done;                      // ygemm completion counter

__device__ __forceinline__ float bf2f(ushort_t u) {
    return __uint_as_float(((unsigned int)u) << 16);
}
__device__ __forceinline__ ushort_t f2bf(float f) {
    unsigned int x = __float_as_uint(f);
    return (ushort_t)((x + 0x7FFFu + ((x >> 16) & 1u)) >> 16);  // RNE
}

// ---------------------------------------------------------------------------
// Kernel 1: neighbor-index histogram (z depends only on the gathered row ->
// multiplicities make stats over 16384 rows == stats over 524288 samples).
// First 32 blocks also convert W -> bf16. 2048 blocks x 256 thr.
// ---------------------------------------------------------------------------
__global__ void hist_kernel(const float* __restrict__ Wg,
                            const int* __restrict__ nbr) {
    const int tid = threadIdx.x;
    if (blockIdx.x < 32) {                        // W -> bf16 (32768 elems)
        int i = blockIdx.x * 1024 + tid * 4;
        float4 v = ((const float4*)Wg)[i >> 2];
        g_wb[i] = f2bf(v.x); g_wb[i + 1] = f2bf(v.y);
        g_wb[i + 2] = f2bf(v.z); g_wb[i + 3] = f2bf(v.w);
    }
    int gid = blockIdx.x * 256 + tid;             // == NSAMP threads exactly
    int gv  = ((gid >> 17) << 12) + nbr[gid];     // same-batch gathered row
    atomicAdd(&g_mult[gv], 1);                    // ~32 hits/address
}

// ---------------------------------------------------------------------------
// Kernel 2 (fused): per-block 64 contiguous rows ->
//   (a) read fm directly, compute fdist, build bf16 LDS A-tile (no g_fsp),
//   (b) MFMA GEMM vs g_wb: Y[r][c], store bf16,
//   (c) mult-weighted per-channel sum/sumsq -> g_stat atomics,
//   (d) zero g_mult for next call,
//   (e) LAST block: fence-read g_stat, compute BN consts + folded direction
//       coeffs into g_consts, zero g_stat/g_done (self-clean).
// bias b cancels exactly in train-mode BN (z - mean(z)) -> never read.
// ---------------------------------------------------------------------------
__global__ __launch_bounds__(256, 2)
void ygemm_kernel(const float* __restrict__ fm,
                  const float* __restrict__ gamma,
                  const float* __restrict__ beta,
                  const float* __restrict__ dirs) {
    __shared__ ushort_t At[64 * LDA];
    __shared__ float    multS[64];
    __shared__ int      lastS;

    const int tid  = threadIdx.x;
    const int r0   = blockIdx.x * 64;
    const int lane = tid & 63;
    const int wv   = tid >> 6;

    if (tid < 64) multS[tid] = (float)g_mult[r0 + tid];

    // --- A-tile build: wave wv handles rows wv*16 .. wv*16+15 ---
    #pragma unroll
    for (int i = 0; i < 16; ++i) {
        int rloc = wv * 16 + i;
        const float* src = fm + (size_t)(r0 + rloc) * 127;
        float f0 = src[lane];
        float f1 = (lane < 63) ? src[64 + lane] : 0.0f;
        float ss = f0 * f0 + f1 * f1;             // fdist in fp32 (matches ref)
        #pragma unroll
        for (int d = 1; d < 64; d <<= 1) ss += __shfl_xor(ss, d, 64);
        float fd = sqrtf(ss);
        At[rloc * LDA + lane]      = f2bf(f0);
        At[rloc * LDA + 64 + lane] = (lane < 63) ? f2bf(f1) : f2bf(fd);
    }
    __syncthreads();

    if (tid < 64) g_mult[r0 + tid] = 0;           // self-clean for next call

    const int m = lane & 15;
    const int q = lane >> 4;

    floatx4 acc[4][4];
    #pragma unroll
    for (int rt = 0; rt < 4; ++rt)
        #pragma unroll
        for (int ct = 0; ct < 4; ++ct)
            acc[rt][ct] = (floatx4){0.0f, 0.0f, 0.0f, 0.0f};

    #pragma unroll
    for (int kk = 0; kk < 4; ++kk) {
        const int kof = kk * 32 + q * 8;
        short8 af[4];
        #pragma unroll
        for (int rt = 0; rt < 4; ++rt)
            af[rt] = *(const short8*)&At[(rt * 16 + m) * LDA + kof];
        short8 bfr[4];
        #pragma unroll
        for (int ct = 0; ct < 4; ++ct) {
            int ch = wv * 64 + ct * 16 + m;
            bfr[ct] = *(const short8*)(g_wb + ch * CIN + kof);  // B[k][n]=W[n][k]
        }
        #pragma unroll
        for (int rt = 0; rt < 4; ++rt)
            #pragma unroll
            for (int ct = 0; ct < 4; ++ct)
                acc[rt][ct] = __builtin_amdgcn_mfma_f32_16x16x32_bf16(
                    af[rt], bfr[ct], acc[rt][ct], 0, 0, 0);
    }

    #pragma unroll
    for (int ct = 0; ct < 4; ++ct) {
        const int ch = wv * 64 + ct * 16 + m;
        float s = 0.0f, ss = 0.0f;
        #pragma unroll
        for (int rt = 0; rt < 4; ++rt)
            #pragma unroll
            for (int j = 0; j < 4; ++j) {
                int rloc = rt * 16 + q * 4 + j;       // C/D: row=(lane>>4)*4+reg
                ushort_t yb = f2bf(acc[rt][ct][j]);
                g_y[(size_t)(r0 + rloc) * COUT + ch] = yb;
                float yv = bf2f(yb);                  // same value epi will read
                float wm = multS[rloc];
                s  += wm * yv;
                ss += wm * yv * yv;
            }
        s  += __shfl_xor(s, 16, 64);  s  += __shfl_xor(s, 32, 64);
        ss += __shfl_xor(ss, 16, 64); ss += __shfl_xor(ss, 32, 64);
        if (q == 0) {
            atomicAdd(&g_stat[ch], s);
            atomicAdd(&g_stat[256 + ch], ss);
        }
    }

    // --- last-block finalize (device-scope atomics + fences) ---
    __syncthreads();                              // all block atomics issued
    if (tid == 0) {
        __threadfence();
        int old = atomicAdd(&g_done, 1);
        lastS = (old == YBLK - 1) ? 1 : 0;
    }
    __syncthreads();
    if (lastS) {
        __threadfence();
        int c = tid;                              // 256 threads = 256 channels
        float sum = atomicAdd(&g_stat[c], 0.0f);        // coherent read
        float ssq = atomicAdd(&g_stat[256 + c], 0.0f);
        const float invN = 1.0f / (float)NSAMP;
        float mean = sum * invN;
        float var  = fmaxf(ssq * invN - mean * mean, 0.0f);  // biased var
        float inv  = 1.0f / sqrtf(var + 1e-5f);
        float scale = gamma[c] * inv;
        g_consts[c]        = scale;
        g_consts[256 + c]  = beta[c] - mean * scale;
        float d0 = dirs[c];
        g_consts[512 + c]  = d0;                  // directions[0]
        g_consts[768 + c]  = dirs[256 + c] - d0;  // sup_w rows
        g_consts[1024 + c] = dirs[512 + c] - d0;
        g_consts[1280 + c] = dirs[768 + c] - d0;
        g_stat[c] = 0.0f; g_stat[256 + c] = 0.0f; // self-clean
        if (tid == 0) g_done = 0;
    }
}

// ---------------------------------------------------------------------------
// Kernel 3: epilogue. One block (128 thr) per point; thread t owns channels
// {2t, 2t+1}. Row base via readfirstlane -> SGPR-based dword Y loads; dw as
// one ds_read_b128; relu(z)*th folded to z*th (th>=0, vm>=0 invariant);
// 4 independent max accumulators break the 32-deep serial max chain.
// ---------------------------------------------------------------------------
__global__ __launch_bounds__(128, 4)
void epi_kernel(const int* __restrict__ nbr,
                const float* __restrict__ verts,
                float* __restrict__ out) {
    __shared__ int    rows[NN];
    __shared__ float4 dws[NN];

    const int p   = blockIdx.x;
    const int tid = threadIdx.x;

    if (tid < NN) {
        int gv = ((p >> 12) << 12) + nbr[p * NN + tid];
        rows[tid] = gv;
        float dx = verts[gv * 3 + 0] - verts[p * 3 + 0];
        float dy = verts[gv * 3 + 1] - verts[p * 3 + 1];
        float dz = verts[gv * 3 + 2] - verts[p * 3 + 2];
        float nrm = sqrtf(dx * dx + dy * dy + dz * dz);
        float inv = 1.0f / fmaxf(nrm, 1e-12f);            // F.normalize eps
        dws[tid] = make_float4((dx * inv + 1.0f) * 0.5f,
                               (dy * inv + 1.0f) * 0.5f,
                               (dz * inv + 1.0f) * 0.5f, 0.0f);
    }
    __syncthreads();

    const int c2 = tid * 2;
    const floatx2 zero = {0.0f, 0.0f};
    floatx2 sc = *(const floatx2*)&g_consts[c2];
    floatx2 sh = *(const floatx2*)&g_consts[256 + c2];
    floatx2 d0 = *(const floatx2*)&g_consts[512 + c2];
    floatx2 s0 = *(const floatx2*)&g_consts[768 + c2];
    floatx2 s1 = *(const floatx2*)&g_consts[1024 + c2];
    floatx2 s2 = *(const floatx2*)&g_consts[1280 + c2];

    floatx2 vm0 = zero, vm1 = zero, vm2 = zero, vm3 = zero;
    #pragma unroll
    for (int j = 0; j < NN; j += 4) {
        #pragma unroll
        for (int jj = 0; jj < 4; ++jj) {
            int rb = __builtin_amdgcn_readfirstlane(rows[j + jj]);  // SGPR base
            const unsigned int* rp =
                (const unsigned int*)(g_y + (size_t)rb * COUT);
            unsigned int u = rp[tid];             // s[base] + tid*4
            floatx2 y;
            y.x = __uint_as_float(u << 16);           // low bf16
            y.y = __uint_as_float(u & 0xFFFF0000u);   // high bf16
            float4 dw = dws[j + jj];              // one ds_read_b128, broadcast
            floatx2 th = d0 + s0 * dw.x + s1 * dw.y + s2 * dw.z;
            th = __builtin_elementwise_max(th, zero);
            floatx2 zt = (y * sc + sh) * th;      // relu(z)*th == max(z*th,0)
            if      (jj == 0) vm0 = __builtin_elementwise_max(vm0, zt);
            else if (jj == 1) vm1 = __builtin_elementwise_max(vm1, zt);
            else if (jj == 2) vm2 = __builtin_elementwise_max(vm2, zt);
            else              vm3 = __builtin_elementwise_max(vm3, zt);
        }
    }
    floatx2 vm = __builtin_elementwise_max(
        __builtin_elementwise_max(vm0, vm1),
        __builtin_elementwise_max(vm2, vm3));     // accs >= 0 -> clamp built in

    *(floatx2*)(out + (size_t)p * COUT + c2) = vm;
}

// ---------------------------------------------------------------------------
extern "C" void kernel_launch(void* const* d_in, const int* in_sizes, int n_in,
                              void* d_out, int out_size, void* d_ws, size_t ws_size,
                              hipStream_t stream) {
    const int*   nbr   = (const int*)d_in[0];
    const float* verts = (const float*)d_in[1];
    const float* fm    = (const float*)d_in[2];
    const float* dirs  = (const float*)d_in[3];
    const float* Wg    = (const float*)d_in[4];
    // d_in[5] = b: cancels exactly under train-mode BatchNorm -> unused
    const float* gamma = (const float*)d_in[6];
    const float* beta  = (const float*)d_in[7];
    (void)d_ws; (void)ws_size; (void)in_sizes; (void)n_in; (void)out_size;

    hist_kernel<<<dim3(NSAMP / 256), dim3(256), 0, stream>>>(Wg, nbr);
    ygemm_kernel<<<dim3(YBLK), dim3(256), 0, stream>>>(fm, gamma, beta, dirs);
    epi_kernel<<<dim3(NPTS), dim3(128), 0, stream>>>(nbr, verts, (float*)d_out);
}

// Round 10
// 156.054 us; speedup vs baseline: 1.0892x; 1.0892x over previous
//
#include <hip/hip_runtime.h>

typedef unsigned short ushort_t;
typedef __attribute__((ext_vector_type(8))) short short8;   // 8 bf16 payload (4 VGPRs)
typedef __attribute__((ext_vector_type(4))) float floatx4;  // MFMA C/D
typedef __attribute__((ext_vector_type(2))) float floatx2;  // packed fp32 (VOP3P)

#define NN    32
#define CIN   128
#define COUT  256
#define NPTS  16384            // bs*v = 4*4096
#define NSAMP (NPTS * NN)      // 524288
#define LDA   136              // LDS A-tile stride (+16B pad)

// Scratch in .so-resident device globals. SELF-CLEANING invariant: g_mult and
// g_stat are zero at kernel_launch entry (BSS-zero on load; ygemm re-zeroes
// g_mult after reading it, finalize re-zeroes g_stat after reading it), so
// no zeroing dispatch is needed and graph replay is correct.
__device__ ushort_t g_fsp[(size_t)NPTS * 128];   // 4 MB: 127 feats + fdist, bf16
__device__ ushort_t g_wb[COUT * CIN];            // 64 KB: W as bf16
__device__ ushort_t g_y[(size_t)NPTS * COUT];    // 8 MB: Y = fsp * W^T, bf16
__device__ int      g_mult[NPTS];                // gather multiplicity histogram
__device__ float    g_stat[512];                 // sum[256] ++ sumsq[256]
__device__ float    g_consts[1536];              // scale,shift,d0,s0,s1,s2 per ch

__device__ __forceinline__ float bf2f(ushort_t u) {
    return __uint_as_float(((unsigned int)u) << 16);
}
__device__ __forceinline__ ushort_t f2bf(float f) {
    unsigned int x = __float_as_uint(f);
    return (ushort_t)((x + 0x7FFFu + ((x >> 16) & 1u)) >> 16);  // RNE
}

// ---------------------------------------------------------------------------
// Prep (4096 blocks x 256 thr): g_fsp[row] = bf16(fm[row][0..126]) ++
// bf16(||row||_2)  (fdist depends only on the source row -> computed once,
// not per (point,nbr)). Blocks < 32 also convert W -> bf16; threads with
// gid < NSAMP histogram the neighbor indices (multiplicities make stats over
// 16384 distinct rows == stats over all 524288 samples).
// ---------------------------------------------------------------------------
__global__ void prep_kernel(const float* __restrict__ fm,
                            const float* __restrict__ Wg,
                            const int* __restrict__ nbr) {
    const int tid = threadIdx.x;
    if (blockIdx.x < 32) {                        // W -> bf16 (32768 elems)
        int i = blockIdx.x * 1024 + tid * 4;
        float4 v = ((const float4*)Wg)[i >> 2];
        g_wb[i] = f2bf(v.x); g_wb[i + 1] = f2bf(v.y);
        g_wb[i + 2] = f2bf(v.z); g_wb[i + 3] = f2bf(v.w);
    }
    int gid = blockIdx.x * 256 + tid;             // 1,048,576 threads, use half
    if (gid < NSAMP) {
        int gv = ((gid >> 17) << 12) + nbr[gid];  // same-batch gathered row
        atomicAdd(&g_mult[gv], 1);                // ~32 hits/address
    }
    int row  = blockIdx.x * 4 + (tid >> 6);
    int lane = tid & 63;
    const float* src = fm + (size_t)row * 127;
    float f0 = src[lane];
    float f1 = (lane < 63) ? src[64 + lane] : 0.0f;
    float ss = f0 * f0 + f1 * f1;                 // fdist in fp32 (matches ref)
    #pragma unroll
    for (int d = 1; d < 64; d <<= 1) ss += __shfl_xor(ss, d, 64);
    float fd = sqrtf(ss);
    ushort_t* dst = g_fsp + (size_t)row * 128;
    dst[lane]      = f2bf(f0);
    dst[64 + lane] = (lane < 63) ? f2bf(f1) : f2bf(fd);
}

// ---------------------------------------------------------------------------
// Y-GEMM + fused weighted stats (256 blocks x 256 thr / 4 waves).
// Y[r][c] = fsp[r] . W[c] for the 16384 DISTINCT rows; M=64 tile, N=256
// (64 ch per wave), K=128; MFMA 16x16x32 bf16. Epilogue: Y -> bf16 store +
// per-channel mult-weighted sum/sumsq via shfl reduce + 1 atomic/ch/block.
// Zeroes g_mult after use (self-clean for the next call / graph replay).
// ---------------------------------------------------------------------------
__global__ __launch_bounds__(256, 2)
void ygemm_kernel() {
    __shared__ ushort_t At[64 * LDA];
    __shared__ float    multS[64];

    const int tid = threadIdx.x;
    const int r0  = blockIdx.x * 64;

    if (tid < 64) {
        multS[tid] = (float)g_mult[r0 + tid];
        g_mult[r0 + tid] = 0;                     // self-clean
    }
    #pragma unroll
    for (int i = 0; i < 4; ++i) {                 // 16 KB contiguous stage
        int chunk = tid + i * 256;                // 1024 chunks of 16 B
        int r = chunk >> 4;
        int c = chunk & 15;
        const uint4 v = *(const uint4*)(g_fsp + (size_t)(r0 + r) * 128 + c * 8);
        *(uint4*)&At[r * LDA + c * 8] = v;
    }
    __syncthreads();

    const int lane = tid & 63;
    const int w    = tid >> 6;           // wave -> channel strip w*64
    const int m    = lane & 15;
    const int q    = lane >> 4;

    floatx4 acc[4][4];
    #pragma unroll
    for (int rt = 0; rt < 4; ++rt)
        #pragma unroll
        for (int ct = 0; ct < 4; ++ct)
            acc[rt][ct] = (floatx4){0.0f, 0.0f, 0.0f, 0.0f};

    #pragma unroll
    for (int kk = 0; kk < 4; ++kk) {
        const int kof = kk * 32 + q * 8;
        short8 af[4];
        #pragma unroll
        for (int rt = 0; rt < 4; ++rt)
            af[rt] = *(const short8*)&At[(rt * 16 + m) * LDA + kof];
        short8 bfr[4];
        #pragma unroll
        for (int ct = 0; ct < 4; ++ct) {
            int ch = w * 64 + ct * 16 + m;
            bfr[ct] = *(const short8*)(g_wb + ch * CIN + kof);  // B[k][n]=W[n][k]
        }
        #pragma unroll
        for (int rt = 0; rt < 4; ++rt)
            #pragma unroll
            for (int ct = 0; ct < 4; ++ct)
                acc[rt][ct] = __builtin_amdgcn_mfma_f32_16x16x32_bf16(
                    af[rt], bfr[ct], acc[rt][ct], 0, 0, 0);
    }

    #pragma unroll
    for (int ct = 0; ct < 4; ++ct) {
        const int ch = w * 64 + ct * 16 + m;
        float s = 0.0f, ss = 0.0f;
        #pragma unroll
        for (int rt = 0; rt < 4; ++rt)
            #pragma unroll
            for (int j = 0; j < 4; ++j) {
                int rloc = rt * 16 + q * 4 + j;       // C/D: row=(lane>>4)*4+reg
                ushort_t yb = f2bf(acc[rt][ct][j]);
                g_y[(size_t)(r0 + rloc) * COUT + ch] = yb;
                float yv = bf2f(yb);                  // same value epi will read
                float wm = multS[rloc];
                s  += wm * yv;
                ss += wm * yv * yv;
            }
        s  += __shfl_xor(s, 16, 64);  s  += __shfl_xor(s, 32, 64);
        ss += __shfl_xor(ss, 16, 64); ss += __shfl_xor(ss, 32, 64);
        if (q == 0) {
            atomicAdd(&g_stat[ch], s);
            atomicAdd(&g_stat[256 + ch], ss);
        }
    }
}

// ---------------------------------------------------------------------------
// Finalize (1 block): per-channel BN constants + folded direction coeffs.
// bias b cancels exactly in train-mode BN (z - mean(z)) -> never read.
// Zeroes g_stat after use (self-clean).
// ---------------------------------------------------------------------------
__global__ void finalize_kernel(const float* __restrict__ gamma,
                                const float* __restrict__ beta,
                                const float* __restrict__ dirs) {
    int c = threadIdx.x;                          // 256 threads, 1 block
    const float invN = 1.0f / (float)NSAMP;
    float mean = g_stat[c] * invN;
    float var  = fmaxf(g_stat[256 + c] * invN - mean * mean, 0.0f);  // biased
    float inv  = 1.0f / sqrtf(var + 1e-5f);
    g_stat[c] = 0.0f; g_stat[256 + c] = 0.0f;     // self-clean
    float scale = gamma[c] * inv;
    g_consts[c]        = scale;
    g_consts[256 + c]  = beta[c] - mean * scale;
    float d0 = dirs[c];
    g_consts[512 + c]  = d0;                      // directions[0]
    g_consts[768 + c]  = dirs[256 + c] - d0;      // sup_w rows
    g_consts[1024 + c] = dirs[512 + c] - d0;
    g_consts[1280 + c] = dirs[768 + c] - d0;
}

// ---------------------------------------------------------------------------
// Epilogue (16384 blocks x 128 thr): thread t owns channels {2t, 2t+1}.
// Row base via readfirstlane -> SGPR-based dword Y loads; dw as one
// ds_read_b128; relu(z)*th folded to z*th (th>=0, vm>=0 invariant);
// 4 independent max accumulators break the 32-deep serial max chain.
// ---------------------------------------------------------------------------
__global__ __launch_bounds__(128, 4)
void epi_kernel(const int* __restrict__ nbr,
                const float* __restrict__ verts,
                float* __restrict__ out) {
    __shared__ int    rows[NN];
    __shared__ float4 dws[NN];

    const int p   = blockIdx.x;
    const int tid = threadIdx.x;

    if (tid < NN) {
        int gv = ((p >> 12) << 12) + nbr[p * NN + tid];
        rows[tid] = gv;
        float dx = verts[gv * 3 + 0] - verts[p * 3 + 0];
        float dy = verts[gv * 3 + 1] - verts[p * 3 + 1];
        float dz = verts[gv * 3 + 2] - verts[p * 3 + 2];
        float nrm = sqrtf(dx * dx + dy * dy + dz * dz);
        float inv = 1.0f / fmaxf(nrm, 1e-12f);            // F.normalize eps
        dws[tid] = make_float4((dx * inv + 1.0f) * 0.5f,
                               (dy * inv + 1.0f) * 0.5f,
                               (dz * inv + 1.0f) * 0.5f, 0.0f);
    }
    __syncthreads();

    const int c2 = tid * 2;
    const floatx2 zero = {0.0f, 0.0f};
    floatx2 sc = *(const floatx2*)&g_consts[c2];
    floatx2 sh = *(const floatx2*)&g_consts[256 + c2];
    floatx2 d0 = *(const floatx2*)&g_consts[512 + c2];
    floatx2 s0 = *(const floatx2*)&g_consts[768 + c2];
    floatx2 s1 = *(const floatx2*)&g_consts[1024 + c2];
    floatx2 s2 = *(const floatx2*)&g_consts[1280 + c2];

    floatx2 vm0 = zero, vm1 = zero, vm2 = zero, vm3 = zero;
    #pragma unroll
    for (int j = 0; j < NN; j += 4) {
        #pragma unroll
        for (int jj = 0; jj < 4; ++jj) {
            int rb = __builtin_amdgcn_readfirstlane(rows[j + jj]);  // SGPR base
            const unsigned int* rp =
                (const unsigned int*)(g_y + (size_t)rb * COUT);
            unsigned int u = rp[tid];             // s[base] + tid*4
            floatx2 y;
            y.x = __uint_as_float(u << 16);           // low bf16
            y.y = __uint_as_float(u & 0xFFFF0000u);   // high bf16
            float4 dw = dws[j + jj];              // one ds_read_b128, broadcast
            floatx2 th = d0 + s0 * dw.x + s1 * dw.y + s2 * dw.z;
            th = __builtin_elementwise_max(th, zero);
            floatx2 zt = (y * sc + sh) * th;      // relu(z)*th == max(z*th,0)
            if      (jj == 0) vm0 = __builtin_elementwise_max(vm0, zt);
            else if (jj == 1) vm1 = __builtin_elementwise_max(vm1, zt);
            else if (jj == 2) vm2 = __builtin_elementwise_max(vm2, zt);
            else              vm3 = __builtin_elementwise_max(vm3, zt);
        }
    }
    floatx2 vm = __builtin_elementwise_max(
        __builtin_elementwise_max(vm0, vm1),
        __builtin_elementwise_max(vm2, vm3));     // accs >= 0 -> clamp built in

    *(floatx2*)(out + (size_t)p * COUT + c2) = vm;
}

// ---------------------------------------------------------------------------
extern "C" void kernel_launch(void* const* d_in, const int* in_sizes, int n_in,
                              void* d_out, int out_size, void* d_ws, size_t ws_size,
                              hipStream_t stream) {
    const int*   nbr   = (const int*)d_in[0];
    const float* verts = (const float*)d_in[1];
    const float* fm    = (const float*)d_in[2];
    const float* dirs  = (const float*)d_in[3];
    const float* Wg    = (const float*)d_in[4];
    // d_in[5] = b: cancels exactly under train-mode BatchNorm -> unused
    const float* gamma = (const float*)d_in[6];
    const float* beta  = (const float*)d_in[7];
    (void)d_ws; (void)ws_size; (void)in_sizes; (void)n_in; (void)out_size;

    prep_kernel<<<dim3(NPTS / 4), dim3(256), 0, stream>>>(fm, Wg, nbr);
    ygemm_kernel<<<dim3(NPTS / 64), dim3(256), 0, stream>>>();
    finalize_kernel<<<dim3(1), dim3(256), 0, stream>>>(gamma, beta, dirs);
    epi_kernel<<<dim3(NPTS), dim3(128), 0, stream>>>(nbr, verts, (float*)d_out);
}